// Round 1
// baseline (1491.140 us; speedup 1.0000x reference)
//
#include <hip/hip_runtime.h>
#include <math.h>

#define N_NODES 50000
#define D 160
#define H 5
#define C 32
#define HC 160
#define E_EDGES 800000
#define ED 16
#define HID 512
#define EPS 1e-5f
#define NEG_SLOPE 0.2f

// ---------------- proj: xl = x@Wl+bl, xr = x@Wr+br ----------------
#define GP 8
__global__ __launch_bounds__(160) void proj_kernel(
    const float* __restrict__ x,
    const float* __restrict__ Wl, const float* __restrict__ bl,
    const float* __restrict__ Wr, const float* __restrict__ br,
    float* __restrict__ xl, float* __restrict__ xr)
{
  __shared__ float xs[GP][D];
  int t = threadIdx.x;
  int n0 = blockIdx.x * GP;
  for (int g = 0; g < GP; ++g) {
    int n = n0 + g;
    if (n < N_NODES) xs[g][t] = x[n*D + t];
  }
  __syncthreads();
  float accl[GP], accr[GP];
#pragma unroll
  for (int g = 0; g < GP; ++g) { accl[g] = bl[t]; accr[g] = br[t]; }
  for (int k = 0; k < D; ++k) {
    float wl = Wl[k*HC + t], wr = Wr[k*HC + t];
#pragma unroll
    for (int g = 0; g < GP; ++g) {
      accl[g] += xs[g][k]*wl;
      accr[g] += xs[g][k]*wr;
    }
  }
  for (int g = 0; g < GP; ++g) {
    int n = n0 + g;
    if (n < N_NODES) { xl[n*HC+t] = accl[g]; xr[n*HC+t] = accr[g]; }
  }
}

// ---------------- CSR build ----------------
__global__ void count_kernel(const int* __restrict__ ei, int* __restrict__ cnt) {
  int e = blockIdx.x*blockDim.x + threadIdx.x;
  if (e < E_EDGES) atomicAdd(&cnt[ei[E_EDGES + e]], 1);
}

__global__ __launch_bounds__(1024) void scan_kernel(const int* __restrict__ cnt,
                                                    int* __restrict__ offs) {
  const int PER = (N_NODES + 1023)/1024; // 49
  int t = threadIdx.x;
  int start = t*PER;
  int sum = 0;
  for (int i = 0; i < PER; ++i) {
    int idx = start + i;
    if (idx < N_NODES) sum += cnt[idx];
  }
  int lane = t & 63, wid = t >> 6;
  int v = sum;
  for (int off = 1; off < 64; off <<= 1) {
    int u = __shfl_up(v, off, 64);
    if (lane >= off) v += u;
  }
  __shared__ int wsums[16];
  if (lane == 63) wsums[wid] = v;
  __syncthreads();
  if (wid == 0) {
    int w = (lane < 16) ? wsums[lane] : 0;
    for (int off = 1; off < 16; off <<= 1) {
      int u = __shfl_up(w, off, 64);
      if (lane >= off) w += u;
    }
    if (lane < 16) wsums[lane] = w;
  }
  __syncthreads();
  int excl = v - sum + (wid > 0 ? wsums[wid-1] : 0);
  int run = excl;
  for (int i = 0; i < PER; ++i) {
    int idx = start + i;
    if (idx < N_NODES) { offs[idx] = run; run += cnt[idx]; }
  }
  if (t == 1023) offs[N_NODES] = run;
}

__global__ void scatter_kernel(const int* __restrict__ ei, const int* __restrict__ offs,
                               int* __restrict__ cursor, int* __restrict__ elist) {
  int e = blockIdx.x*blockDim.x + threadIdx.x;
  if (e < E_EDGES) {
    int dmy = ei[E_EDGES + e];
    int slot = atomicAdd(&cursor[dmy], 1);
    elist[offs[dmy] + slot] = e;
  }
}

// ---------------- attention + residual + LN1 ----------------
__global__ __launch_bounds__(160) void attn_kernel(
    const int* __restrict__ ei, const float* __restrict__ eattr,
    const float* __restrict__ xl, const float* __restrict__ xr,
    const float* __restrict__ x,
    const float* __restrict__ We, const float* __restrict__ att,
    const float* __restrict__ b_gat, const float* __restrict__ g1, const float* __restrict__ b1,
    const int* __restrict__ offs, const int* __restrict__ elist,
    float* __restrict__ out)
{
  __shared__ float sWe[ED][HC];
  int i = blockIdx.x;
  int t = threadIdx.x;
  for (int k = 0; k < ED; ++k) sWe[k][t] = We[k*HC + t];
  float a_t = att[t];            // att flattened [H][C]
  float xr_t = xr[i*HC + t];
  float agg = 0.f, denom = 0.f;
  int e0 = offs[i], e1 = offs[i+1];
  __syncthreads();
  for (int j = e0; j < e1; ++j) {
    int eid = elist[j];
    int src = ei[eid];
    const float* ar = &eattr[eid*ED];
    float ea = 0.f;
#pragma unroll
    for (int k = 0; k < ED; ++k) ea += ar[k]*sWe[k][t];
    float xlv = xl[src*HC + t];
    float v = xlv + xr_t + ea;
    v = v > 0.f ? v : NEG_SLOPE*v;
    float p = a_t * v;
#pragma unroll
    for (int m = 16; m >= 1; m >>= 1) p += __shfl_xor(p, m, 32);
    float ex = expf(p);   // softmax shift-invariant; scores are O(1) here
    denom += ex;
    agg += ex * xlv;
  }
  float attn = (denom > 0.f) ? agg/denom : 0.f;
  float val = x[i*HC + t] + attn + b_gat[t];
  // block LayerNorm over 160 values
  float s1 = val, s2 = val*val;
#pragma unroll
  for (int m = 16; m >= 1; m >>= 1) { s1 += __shfl_xor(s1, m, 32); s2 += __shfl_xor(s2, m, 32); }
  __shared__ float gs1[5], gs2[5];
  __shared__ float smu, srstd;
  if ((t & 31) == 0) { gs1[t>>5] = s1; gs2[t>>5] = s2; }
  __syncthreads();
  if (t == 0) {
    float a = 0.f, b = 0.f;
    for (int g = 0; g < 5; ++g) { a += gs1[g]; b += gs2[g]; }
    float mu = a/160.f, var = b/160.f - mu*mu;
    smu = mu; srstd = rsqrtf(var + EPS);
  }
  __syncthreads();
  out[i*HC + t] = (val - smu)*srstd*g1[t] + b1[t];
}

// ---------------- MLP1 + SELU + LN(512) ----------------
#define G5 16
__global__ __launch_bounds__(512) void mlp1_kernel(
    const float* __restrict__ outb,
    const float* __restrict__ W1, const float* __restrict__ b1m,
    const float* __restrict__ gm, const float* __restrict__ bm,
    float* __restrict__ hbuf)
{
  __shared__ float xs[G5][D];  // 10 KB
  int t = threadIdx.x;
  int n0 = blockIdx.x * G5;
  for (int idx = t; idx < G5*D; idx += 512) {
    int g = idx / D, k = idx % D;
    xs[g][k] = outb[(n0+g)*D + k];
  }
  __syncthreads();
  float acc[G5];
#pragma unroll
  for (int g = 0; g < G5; ++g) acc[g] = b1m[t];
  for (int k = 0; k < D; ++k) {
    float w = W1[k*HID + t];
#pragma unroll
    for (int g = 0; g < G5; ++g) acc[g] += xs[g][k]*w;
  }
#pragma unroll
  for (int g = 0; g < G5; ++g) {
    float v = acc[g];
    acc[g] = 1.0507009873554805f * (v > 0.f ? v : 1.6732632423543772f*(expf(v)-1.f));
  }
  // LN over 512 for each of the 16 rows
  __shared__ float ps1[8][G5], ps2[8][G5];
  int lane = t & 63, wid = t >> 6;
#pragma unroll
  for (int g = 0; g < G5; ++g) {
    float s1 = acc[g], s2 = acc[g]*acc[g];
#pragma unroll
    for (int m = 32; m >= 1; m >>= 1) { s1 += __shfl_xor(s1, m, 64); s2 += __shfl_xor(s2, m, 64); }
    if (lane == 0) { ps1[wid][g] = s1; ps2[wid][g] = s2; }
  }
  __syncthreads();
  __shared__ float mu_s[G5], rs_s[G5];
  if (t < G5) {
    float a = 0.f, b = 0.f;
    for (int w = 0; w < 8; ++w) { a += ps1[w][t]; b += ps2[w][t]; }
    float mu = a/512.f, var = b/512.f - mu*mu;
    mu_s[t] = mu; rs_s[t] = rsqrtf(var + EPS);
  }
  __syncthreads();
#pragma unroll
  for (int g = 0; g < G5; ++g)
    hbuf[(size_t)(n0+g)*HID + t] = (acc[g]-mu_s[g])*rs_s[g]*gm[t] + bm[t];
}

// ---------------- MLP2 + residual + LN2 -> d_out ----------------
__global__ __launch_bounds__(160) void mlp2_kernel(
    const float* __restrict__ hbuf,
    const float* __restrict__ W2, const float* __restrict__ b2m,
    const float* __restrict__ outb, const float* __restrict__ g2, const float* __restrict__ b2,
    float* __restrict__ y)
{
  __shared__ float hs[G5][HID]; // 32 KB
  int t = threadIdx.x; int n0 = blockIdx.x*G5;
  for (int idx = t; idx < G5*HID; idx += 160) {
    int g = idx / HID, k = idx % HID;
    hs[g][k] = hbuf[(size_t)(n0+g)*HID + k];
  }
  __syncthreads();
  float acc[G5];
#pragma unroll
  for (int g = 0; g < G5; ++g) acc[g] = b2m[t];
  for (int k = 0; k < HID; ++k) {
    float w = W2[k*D + t];
#pragma unroll
    for (int g = 0; g < G5; ++g) acc[g] += hs[g][k]*w;
  }
  __shared__ float gsum[5], gsq[5], smu, srs;
  for (int g = 0; g < G5; ++g) {
    float val = outb[(n0+g)*D + t] + acc[g];
    float s1 = val, s2 = val*val;
#pragma unroll
    for (int m = 16; m >= 1; m >>= 1) { s1 += __shfl_xor(s1, m, 32); s2 += __shfl_xor(s2, m, 32); }
    if ((t & 31) == 0) { gsum[t>>5] = s1; gsq[t>>5] = s2; }
    __syncthreads();
    if (t == 0) {
      float a = 0.f, b = 0.f;
      for (int q = 0; q < 5; ++q) { a += gsum[q]; b += gsq[q]; }
      float mu = a/160.f, var = b/160.f - mu*mu;
      smu = mu; srs = rsqrtf(var + EPS);
    }
    __syncthreads();
    y[(n0+g)*D + t] = (val - smu)*srs*g2[t] + b2[t];
    __syncthreads();
  }
}

extern "C" void kernel_launch(void* const* d_in, const int* in_sizes, int n_in,
                              void* d_out, int out_size, void* d_ws, size_t ws_size,
                              hipStream_t stream) {
  const float* x        = (const float*)d_in[0];
  const int*   ei       = (const int*)d_in[1];
  const float* eattr    = (const float*)d_in[2];
  // d_in[3] = u (unused), d_in[4] = batch (unused)
  const float* Wl   = (const float*)d_in[5];
  const float* bl   = (const float*)d_in[6];
  const float* Wr   = (const float*)d_in[7];
  const float* br   = (const float*)d_in[8];
  const float* We   = (const float*)d_in[9];
  const float* att  = (const float*)d_in[10];
  const float* bgat = (const float*)d_in[11];
  const float* g1   = (const float*)d_in[12];
  const float* b1   = (const float*)d_in[13];
  const float* Wm1  = (const float*)d_in[14];
  const float* bm1  = (const float*)d_in[15];
  const float* gm   = (const float*)d_in[16];
  const float* bm   = (const float*)d_in[17];
  const float* Wm2  = (const float*)d_in[18];
  const float* bm2  = (const float*)d_in[19];
  const float* g2   = (const float*)d_in[20];
  const float* b2   = (const float*)d_in[21];
  float* y = (float*)d_out;

  // workspace layout (floats first, then ints)
  char* p = (char*)d_ws;
  float* xl   = (float*)p;                 p += (size_t)N_NODES*HC*4;
  float* xr   = (float*)p;                 p += (size_t)N_NODES*HC*4;
  float* outb = (float*)p;                 p += (size_t)N_NODES*D*4;
  float* hbuf = (float*)p;                 p += (size_t)N_NODES*HID*4;
  int* cnt    = (int*)p;                   p += (size_t)N_NODES*4;
  int* offs   = (int*)p;                   p += (size_t)(N_NODES+1)*4;
  int* cursor = (int*)p;                   p += (size_t)N_NODES*4;
  int* elist  = (int*)p;                   p += (size_t)E_EDGES*4;

  hipMemsetAsync(cnt, 0, (size_t)N_NODES*4, stream);
  hipMemsetAsync(cursor, 0, (size_t)N_NODES*4, stream);

  proj_kernel<<<N_NODES/GP, 160, 0, stream>>>(x, Wl, bl, Wr, br, xl, xr);
  count_kernel<<<(E_EDGES+255)/256, 256, 0, stream>>>(ei, cnt);
  scan_kernel<<<1, 1024, 0, stream>>>(cnt, offs);
  scatter_kernel<<<(E_EDGES+255)/256, 256, 0, stream>>>(ei, offs, cursor, elist);
  attn_kernel<<<N_NODES, 160, 0, stream>>>(ei, eattr, xl, xr, x, We, att, bgat,
                                           g1, b1, offs, elist, outb);
  mlp1_kernel<<<N_NODES/G5, 512, 0, stream>>>(outb, Wm1, bm1, gm, bm, hbuf);
  mlp2_kernel<<<N_NODES/G5, 160, 0, stream>>>(hbuf, Wm2, bm2, outb, g2, b2, y);
}

// Round 2
// 808.354 us; speedup vs baseline: 1.8447x; 1.8447x over previous
//
#include <hip/hip_runtime.h>
#include <math.h>

#define N_NODES 50000
#define D 160
#define H 5
#define C 32
#define HC 160
#define E_EDGES 800000
#define ED 16
#define HID 512
#define EPS 1e-5f
#define NEG_SLOPE 0.2f

typedef __attribute__((ext_vector_type(8))) short bf16x8;
typedef __attribute__((ext_vector_type(4))) float f32x4;
typedef __attribute__((ext_vector_type(4))) short short4v;

__device__ inline float bf2f(short s) {
  unsigned u = ((unsigned)(unsigned short)s) << 16;
  return __builtin_bit_cast(float, u);
}
__device__ inline short f2bf(float f) {
  unsigned u = __builtin_bit_cast(unsigned, f);
  u = u + 0x7fffu + ((u >> 16) & 1u);
  return (short)(u >> 16);
}
__device__ inline float selu_f(float v) {
  return 1.0507009873554805f * (v > 0.f ? v : 1.6732632423543772f * (__expf(v) - 1.f));
}

// ---------------- weight prep: transpose + bf16 ----------------
__global__ void prep_weights(const float* __restrict__ Wl, const float* __restrict__ Wr,
                             const float* __restrict__ Wm1, const float* __restrict__ Wm2,
                             short* __restrict__ WlT, short* __restrict__ WrT,
                             short* __restrict__ W1T, short* __restrict__ W2T) {
  int i = blockIdx.x * blockDim.x + threadIdx.x;
  if (i < 25600) { int n = i / 160, k = i % 160; WlT[n*160 + k] = f2bf(Wl[k*160 + n]); return; }
  i -= 25600;
  if (i < 25600) { int n = i / 160, k = i % 160; WrT[n*160 + k] = f2bf(Wr[k*160 + n]); return; }
  i -= 25600;
  if (i < 81920) { int n = i / 160, k = i % 160; W1T[n*160 + k] = f2bf(Wm1[k*512 + n]); return; }
  i -= 81920;
  if (i < 81920) { int n = i / 512, k = i % 512; W2T[n*512 + k] = f2bf(Wm2[k*160 + n]); return; }
}

// ---------------- convert x to bf16 ----------------
__global__ void convert_x(const float* __restrict__ x, short* __restrict__ xb) {
  int i = blockIdx.x * blockDim.x + threadIdx.x;
  if (i < N_NODES * D / 8) {
    const float4* s = (const float4*)(x + (size_t)i * 8);
    float4 a = s[0], b = s[1];
    bf16x8 o;
    o[0] = f2bf(a.x); o[1] = f2bf(a.y); o[2] = f2bf(a.z); o[3] = f2bf(a.w);
    o[4] = f2bf(b.x); o[5] = f2bf(b.y); o[6] = f2bf(b.z); o[7] = f2bf(b.w);
    *(bf16x8*)(xb + (size_t)i * 8) = o;
  }
}

// ---------------- proj MFMA: xl = x@Wl+bl, xr = x@Wr+br (bf16 out) ----------------
__global__ __launch_bounds__(256) void proj_mfma(
    const short* __restrict__ xb, const short* __restrict__ WlT, const short* __restrict__ WrT,
    const float* __restrict__ bl, const float* __restrict__ br,
    short* __restrict__ xl, short* __restrict__ xr)
{
  __shared__ short As[64][40];   // 64 rows x 32 k, padded stride 40 shorts (80 B)
  int t = threadIdx.x;
  int wave = t >> 6, lane = t & 63;
  int lq = lane >> 4, lc = lane & 15;
  int row0 = blockIdx.x * 64;
  f32x4 accl[10] = {}, accr[10] = {};
  for (int kt = 0; kt < 5; ++kt) {
    int k0 = kt * 32;
    {
      int r = t >> 2, seg = t & 3;
      int gr = min(row0 + r, N_NODES - 1);
      bf16x8 v = *(const bf16x8*)&xb[(size_t)gr * 160 + k0 + seg * 8];
      *(bf16x8*)&As[r][seg * 8] = v;
    }
    __syncthreads();
    bf16x8 af = *(bf16x8*)&As[wave * 16 + lc][lq * 8];
#pragma unroll
    for (int ct = 0; ct < 10; ++ct) {
      int cc = ct * 16 + lc;
      bf16x8 bfl = *(const bf16x8*)&WlT[cc * 160 + k0 + lq * 8];
      accl[ct] = __builtin_amdgcn_mfma_f32_16x16x32_bf16(af, bfl, accl[ct], 0, 0, 0);
      bf16x8 bfr = *(const bf16x8*)&WrT[cc * 160 + k0 + lq * 8];
      accr[ct] = __builtin_amdgcn_mfma_f32_16x16x32_bf16(af, bfr, accr[ct], 0, 0, 0);
    }
    __syncthreads();
  }
#pragma unroll
  for (int ct = 0; ct < 10; ++ct) {
    int col = ct * 16 + lc;
    float bbl = bl[col], bbr = br[col];
#pragma unroll
    for (int rg = 0; rg < 4; ++rg) {
      int row = row0 + wave * 16 + lq * 4 + rg;
      if (row < N_NODES) {
        xl[(size_t)row * 160 + col] = f2bf(accl[ct][rg] + bbl);
        xr[(size_t)row * 160 + col] = f2bf(accr[ct][rg] + bbr);
      }
    }
  }
}

// ---------------- CSR build ----------------
__global__ void count_kernel(const int* __restrict__ ei, int* __restrict__ cnt) {
  int e = blockIdx.x * blockDim.x + threadIdx.x;
  if (e < E_EDGES) atomicAdd(&cnt[ei[E_EDGES + e]], 1);
}

__global__ __launch_bounds__(1024) void scan_kernel(const int* __restrict__ cnt,
                                                    int* __restrict__ offs) {
  const int PER = (N_NODES + 1023) / 1024;
  int t = threadIdx.x;
  int start = t * PER;
  int sum = 0;
  for (int i = 0; i < PER; ++i) {
    int idx = start + i;
    if (idx < N_NODES) sum += cnt[idx];
  }
  int lane = t & 63, wid = t >> 6;
  int v = sum;
  for (int off = 1; off < 64; off <<= 1) {
    int u = __shfl_up(v, off, 64);
    if (lane >= off) v += u;
  }
  __shared__ int wsums[16];
  if (lane == 63) wsums[wid] = v;
  __syncthreads();
  if (wid == 0) {
    int w = (lane < 16) ? wsums[lane] : 0;
    for (int off = 1; off < 16; off <<= 1) {
      int u = __shfl_up(w, off, 64);
      if (lane >= off) w += u;
    }
    if (lane < 16) wsums[lane] = w;
  }
  __syncthreads();
  int excl = v - sum + (wid > 0 ? wsums[wid - 1] : 0);
  int run = excl;
  for (int i = 0; i < PER; ++i) {
    int idx = start + i;
    if (idx < N_NODES) { offs[idx] = run; run += cnt[idx]; }
  }
  if (t == 1023) offs[N_NODES] = run;
}

// scatter: CSR-order srcs + bf16 edge_attr (kills dependent-load chain in attn)
__global__ void scatter2(const int* __restrict__ ei, const float* __restrict__ eattr,
                         const int* __restrict__ offs, int* __restrict__ cursor,
                         int* __restrict__ srcs, short* __restrict__ eacsr) {
  int e = blockIdx.x * blockDim.x + threadIdx.x;
  if (e < E_EDGES) {
    int dst = ei[E_EDGES + e];
    int src = ei[e];
    int slot = atomicAdd(&cursor[dst], 1);
    int j = offs[dst] + slot;
    srcs[j] = src;
    const float4* s = (const float4*)&eattr[(size_t)e * ED];
    float4 v0 = s[0], v1 = s[1], v2 = s[2], v3 = s[3];
    short* o = eacsr + (size_t)j * ED;
    short4v w0, w1, w2, w3;
    w0[0]=f2bf(v0.x); w0[1]=f2bf(v0.y); w0[2]=f2bf(v0.z); w0[3]=f2bf(v0.w);
    w1[0]=f2bf(v1.x); w1[1]=f2bf(v1.y); w1[2]=f2bf(v1.z); w1[3]=f2bf(v1.w);
    w2[0]=f2bf(v2.x); w2[1]=f2bf(v2.y); w2[2]=f2bf(v2.z); w2[3]=f2bf(v2.w);
    w3[0]=f2bf(v3.x); w3[1]=f2bf(v3.y); w3[2]=f2bf(v3.z); w3[3]=f2bf(v3.w);
    *(short4v*)(o + 0) = w0; *(short4v*)(o + 4) = w1;
    *(short4v*)(o + 8) = w2; *(short4v*)(o + 12) = w3;
  }
}

// ---------------- attention + residual + LN1 ----------------
__global__ __launch_bounds__(160) void attn_kernel(
    const short* __restrict__ eacsr, const int* __restrict__ srcs,
    const short* __restrict__ xl, const short* __restrict__ xr,
    const float* __restrict__ x, const float* __restrict__ We,
    const float* __restrict__ att, const float* __restrict__ b_gat,
    const float* __restrict__ g1, const float* __restrict__ b1,
    const int* __restrict__ offs,
    float* __restrict__ outb, short* __restrict__ outb_bf)
{
  __shared__ float sWe[ED][HC];
  int i = blockIdx.x;
  int t = threadIdx.x;
  for (int k = 0; k < ED; ++k) sWe[k][t] = We[k*HC + t];
  float a_t = att[t];
  float xr_t = bf2f(xr[(size_t)i*HC + t]);
  int e0 = offs[i], e1 = offs[i+1];
  __syncthreads();
  float agg = 0.f, denom = 0.f;
  for (int j = e0; j < e1; ++j) {
    int src = srcs[j];
    bf16x8 ev0 = *(const bf16x8*)&eacsr[(size_t)j*ED];
    bf16x8 ev1 = *(const bf16x8*)&eacsr[(size_t)j*ED + 8];
    float ea = 0.f;
#pragma unroll
    for (int k = 0; k < 8; ++k) ea += bf2f(ev0[k]) * sWe[k][t];
#pragma unroll
    for (int k = 0; k < 8; ++k) ea += bf2f(ev1[k]) * sWe[k+8][t];
    float xlv = bf2f(xl[(size_t)src*HC + t]);
    float v = xlv + xr_t + ea;
    v = v > 0.f ? v : NEG_SLOPE*v;
    float p = a_t * v;
#pragma unroll
    for (int m = 16; m >= 1; m >>= 1) p += __shfl_xor(p, m, 32);
    float ex = __expf(p);   // softmax shift-invariant; scores are O(1)
    denom += ex;
    agg += ex * xlv;
  }
  float attn = (denom > 0.f) ? agg/denom : 0.f;
  float val = x[(size_t)i*HC + t] + attn + b_gat[t];
  float s1 = val, s2 = val*val;
#pragma unroll
  for (int m = 16; m >= 1; m >>= 1) { s1 += __shfl_xor(s1, m, 32); s2 += __shfl_xor(s2, m, 32); }
  __shared__ float gs1[5], gs2[5];
  __shared__ float smu, srstd;
  if ((t & 31) == 0) { gs1[t>>5] = s1; gs2[t>>5] = s2; }
  __syncthreads();
  if (t == 0) {
    float a = 0.f, b = 0.f;
    for (int g = 0; g < 5; ++g) { a += gs1[g]; b += gs2[g]; }
    float mu = a/160.f, var = b/160.f - mu*mu;
    smu = mu; srstd = rsqrtf(var + EPS);
  }
  __syncthreads();
  float o = (val - smu)*srstd*g1[t] + b1[t];
  outb[(size_t)i*HC + t] = o;
  outb_bf[(size_t)i*HC + t] = f2bf(o);
}

// ---------------- mlp1 MFMA: h = LN(selu(outb@Wm1+b)) -> bf16 ----------------
__global__ __launch_bounds__(256) void mlp1_mfma(
    const short* __restrict__ ab, const short* __restrict__ W1T,
    const float* __restrict__ b1m, const float* __restrict__ gm, const float* __restrict__ bm,
    short* __restrict__ h)
{
  __shared__ short As[32][40];
  __shared__ float ps1[4][32], ps2[4][32];
  int t = threadIdx.x;
  int wave = t >> 6, lane = t & 63;
  int lq = lane >> 4, lc = lane & 15;
  int row0 = blockIdx.x * 32;
  f32x4 acc[2][8] = {};
  for (int kt = 0; kt < 5; ++kt) {
    int k0 = kt * 32;
    if (t < 128) {
      int r = t >> 2, seg = t & 3;
      int gr = min(row0 + r, N_NODES - 1);
      bf16x8 v = *(const bf16x8*)&ab[(size_t)gr * 160 + k0 + seg * 8];
      *(bf16x8*)&As[r][seg * 8] = v;
    }
    __syncthreads();
    bf16x8 af0 = *(bf16x8*)&As[lc][lq * 8];
    bf16x8 af1 = *(bf16x8*)&As[16 + lc][lq * 8];
#pragma unroll
    for (int ct = 0; ct < 8; ++ct) {
      int cc = wave * 128 + ct * 16 + lc;
      bf16x8 bfv = *(const bf16x8*)&W1T[cc * 160 + k0 + lq * 8];
      acc[0][ct] = __builtin_amdgcn_mfma_f32_16x16x32_bf16(af0, bfv, acc[0][ct], 0, 0, 0);
      acc[1][ct] = __builtin_amdgcn_mfma_f32_16x16x32_bf16(af1, bfv, acc[1][ct], 0, 0, 0);
    }
    __syncthreads();
  }
  float s1[2][4] = {}, s2[2][4] = {};
#pragma unroll
  for (int rt = 0; rt < 2; ++rt)
#pragma unroll
    for (int ct = 0; ct < 8; ++ct)
#pragma unroll
      for (int rg = 0; rg < 4; ++rg) {
        int cc = wave * 128 + ct * 16 + lc;
        float v = selu_f(acc[rt][ct][rg] + b1m[cc]);
        acc[rt][ct][rg] = v;
        s1[rt][rg] += v; s2[rt][rg] += v * v;
      }
#pragma unroll
  for (int m = 1; m <= 8; m <<= 1) {
#pragma unroll
    for (int rt = 0; rt < 2; ++rt)
#pragma unroll
      for (int rg = 0; rg < 4; ++rg) {
        s1[rt][rg] += __shfl_xor(s1[rt][rg], m, 64);
        s2[rt][rg] += __shfl_xor(s2[rt][rg], m, 64);
      }
  }
  if (lc == 0) {
#pragma unroll
    for (int rt = 0; rt < 2; ++rt)
#pragma unroll
      for (int rg = 0; rg < 4; ++rg) {
        ps1[wave][rt * 16 + lq * 4 + rg] = s1[rt][rg];
        ps2[wave][rt * 16 + lq * 4 + rg] = s2[rt][rg];
      }
  }
  __syncthreads();
  float mu[2][4], rstd[2][4];
#pragma unroll
  for (int rt = 0; rt < 2; ++rt)
#pragma unroll
    for (int rg = 0; rg < 4; ++rg) {
      int rl = rt * 16 + lq * 4 + rg;
      float a = ps1[0][rl] + ps1[1][rl] + ps1[2][rl] + ps1[3][rl];
      float b = ps2[0][rl] + ps2[1][rl] + ps2[2][rl] + ps2[3][rl];
      float m_ = a * (1.f / 512.f);
      float var = b * (1.f / 512.f) - m_ * m_;
      mu[rt][rg] = m_; rstd[rt][rg] = rsqrtf(var + EPS);
    }
#pragma unroll
  for (int rt = 0; rt < 2; ++rt)
#pragma unroll
    for (int ct = 0; ct < 8; ++ct)
#pragma unroll
      for (int rg = 0; rg < 4; ++rg) {
        int row = row0 + rt * 16 + lq * 4 + rg;
        int cc = wave * 128 + ct * 16 + lc;
        if (row < N_NODES)
          h[(size_t)row * 512 + cc] =
              f2bf((acc[rt][ct][rg] - mu[rt][rg]) * rstd[rt][rg] * gm[cc] + bm[cc]);
      }
}

// ---------------- mlp2 MFMA: y = LN(outb + h@Wm2 + b) ----------------
__global__ __launch_bounds__(256) void mlp2_mfma(
    const short* __restrict__ hb, const short* __restrict__ W2T,
    const float* __restrict__ b2m, const float* __restrict__ outb,
    const float* __restrict__ g2, const float* __restrict__ b2,
    float* __restrict__ y)
{
  __shared__ short As[64][40];
  int t = threadIdx.x;
  int wave = t >> 6, lane = t & 63;
  int lq = lane >> 4, lc = lane & 15;
  int row0 = blockIdx.x * 64;
  f32x4 acc[10] = {};
  for (int kt = 0; kt < 16; ++kt) {
    int k0 = kt * 32;
    {
      int r = t >> 2, seg = t & 3;
      int gr = min(row0 + r, N_NODES - 1);
      bf16x8 v = *(const bf16x8*)&hb[(size_t)gr * 512 + k0 + seg * 8];
      *(bf16x8*)&As[r][seg * 8] = v;
    }
    __syncthreads();
    bf16x8 af = *(bf16x8*)&As[wave * 16 + lc][lq * 8];
#pragma unroll
    for (int ct = 0; ct < 10; ++ct) {
      int cc = ct * 16 + lc;
      bf16x8 bfv = *(const bf16x8*)&W2T[cc * 512 + k0 + lq * 8];
      acc[ct] = __builtin_amdgcn_mfma_f32_16x16x32_bf16(af, bfv, acc[ct], 0, 0, 0);
    }
    __syncthreads();
  }
  float s1[4] = {}, s2[4] = {};
#pragma unroll
  for (int ct = 0; ct < 10; ++ct) {
    int col = ct * 16 + lc;
#pragma unroll
    for (int rg = 0; rg < 4; ++rg) {
      int rowl = min(row0 + wave * 16 + lq * 4 + rg, N_NODES - 1);
      float v = acc[ct][rg] + b2m[col] + outb[(size_t)rowl * 160 + col];
      acc[ct][rg] = v;
      s1[rg] += v; s2[rg] += v * v;
    }
  }
#pragma unroll
  for (int m = 1; m <= 8; m <<= 1) {
#pragma unroll
    for (int rg = 0; rg < 4; ++rg) {
      s1[rg] += __shfl_xor(s1[rg], m, 64);
      s2[rg] += __shfl_xor(s2[rg], m, 64);
    }
  }
  float mu[4], rstd[4];
#pragma unroll
  for (int rg = 0; rg < 4; ++rg) {
    float m_ = s1[rg] * (1.f / 160.f);
    float var = s2[rg] * (1.f / 160.f) - m_ * m_;
    mu[rg] = m_; rstd[rg] = rsqrtf(var + EPS);
  }
#pragma unroll
  for (int ct = 0; ct < 10; ++ct) {
    int col = ct * 16 + lc;
#pragma unroll
    for (int rg = 0; rg < 4; ++rg) {
      int row = row0 + wave * 16 + lq * 4 + rg;
      if (row < N_NODES)
        y[(size_t)row * 160 + col] = (acc[ct][rg] - mu[rg]) * rstd[rg] * g2[col] + b2[col];
    }
  }
}

extern "C" void kernel_launch(void* const* d_in, const int* in_sizes, int n_in,
                              void* d_out, int out_size, void* d_ws, size_t ws_size,
                              hipStream_t stream) {
  const float* x     = (const float*)d_in[0];
  const int*   ei    = (const int*)d_in[1];
  const float* eattr = (const float*)d_in[2];
  const float* Wl    = (const float*)d_in[5];
  const float* bl    = (const float*)d_in[6];
  const float* Wr    = (const float*)d_in[7];
  const float* br    = (const float*)d_in[8];
  const float* We    = (const float*)d_in[9];
  const float* att   = (const float*)d_in[10];
  const float* bgat  = (const float*)d_in[11];
  const float* g1    = (const float*)d_in[12];
  const float* b1    = (const float*)d_in[13];
  const float* Wm1   = (const float*)d_in[14];
  const float* bm1   = (const float*)d_in[15];
  const float* gm    = (const float*)d_in[16];
  const float* bm    = (const float*)d_in[17];
  const float* Wm2   = (const float*)d_in[18];
  const float* bm2   = (const float*)d_in[19];
  const float* g2    = (const float*)d_in[20];
  const float* b2    = (const float*)d_in[21];
  float* y = (float*)d_out;

  char* p = (char*)d_ws;
  auto alloc = [&](size_t bytes) {
    void* q = p;
    p += (bytes + 255) & ~(size_t)255;
    return q;
  };
  short* xb      = (short*)alloc((size_t)N_NODES * 160 * 2);
  short* xlb     = (short*)alloc((size_t)N_NODES * 160 * 2);
  short* xrb     = (short*)alloc((size_t)N_NODES * 160 * 2);
  float* outb    = (float*)alloc((size_t)N_NODES * 160 * 4);
  short* outb_bf = (short*)alloc((size_t)N_NODES * 160 * 2);
  short* hb      = (short*)alloc((size_t)N_NODES * 512 * 2);
  short* eacsr   = (short*)alloc((size_t)E_EDGES * 16 * 2);
  int*   srcs    = (int*)alloc((size_t)E_EDGES * 4);
  short* WlT     = (short*)alloc(160 * 160 * 2);
  short* WrT     = (short*)alloc(160 * 160 * 2);
  short* W1T     = (short*)alloc(512 * 160 * 2);
  short* W2T     = (short*)alloc(160 * 512 * 2);
  int*   cnt     = (int*)alloc((size_t)N_NODES * 4);
  int*   offs    = (int*)alloc((size_t)(N_NODES + 1) * 4);
  int*   cursor  = (int*)alloc((size_t)N_NODES * 4);

  hipMemsetAsync(cnt, 0, (size_t)N_NODES * 4, stream);
  hipMemsetAsync(cursor, 0, (size_t)N_NODES * 4, stream);

  prep_weights<<<(215040 + 255) / 256, 256, 0, stream>>>(Wl, Wr, Wm1, Wm2, WlT, WrT, W1T, W2T);
  convert_x<<<(N_NODES * 160 / 8 + 255) / 256, 256, 0, stream>>>(x, xb);
  count_kernel<<<(E_EDGES + 255) / 256, 256, 0, stream>>>(ei, cnt);
  scan_kernel<<<1, 1024, 0, stream>>>(cnt, offs);
  scatter2<<<(E_EDGES + 255) / 256, 256, 0, stream>>>(ei, eattr, offs, cursor, srcs, eacsr);
  proj_mfma<<<(N_NODES + 63) / 64, 256, 0, stream>>>(xb, WlT, WrT, bl, br, xlb, xrb);
  attn_kernel<<<N_NODES, 160, 0, stream>>>(eacsr, srcs, xlb, xrb, x, We, att, bgat,
                                           g1, b1, offs, outb, outb_bf);
  mlp1_mfma<<<(N_NODES + 31) / 32, 256, 0, stream>>>(outb_bf, W1T, bm1, gm, bm, hb);
  mlp2_mfma<<<(N_NODES + 63) / 64, 256, 0, stream>>>(hb, W2T, bm2, outb, g2, b2, y);
}